// Round 1
// baseline (571.240 us; speedup 1.0000x reference)
//
#include <hip/hip_runtime.h>

// ---------------------------------------------------------------------------
// GCN 3-layer fused pipeline for MI355X.
//   Layer l: h = X @ Wl ; agg[n] = dinv[n]^2*h[n] + sum_{e:dst=n} norm_e*h[src_e]
//            y = agg + b ; (layers 1,2) y = relu(BN_eval(y))
// CSR (by dst) built on device every call (deterministic inputs -> same CSR).
// ---------------------------------------------------------------------------

// Detect whether edge_index is int32 or int64 on device: if data is int64
// (little-endian), every odd 32-bit word is a high word == 0 (values < 2^31).
// If int32, odd words are random node ids, nonzero w.h.p.
__global__ void detect_dtype_kernel(const int* __restrict__ ei32, int* flag) {
  int t = threadIdx.x;
  int any = 0;
  for (int i = 2 * t + 1; i < 8192; i += 512) any |= (ei32[i] != 0);
  if (any) atomicOr(flag, 1);  // 1 => int32 data
}

__device__ __forceinline__ int edge_val(const int* ei32, const long long* ei64,
                                        int is32, int idx) {
  return is32 ? ei32[idx] : (int)ei64[idx];
}

__global__ void count_deg_kernel(const int* __restrict__ ei32,
                                 const long long* __restrict__ ei64,
                                 const int* __restrict__ flag,
                                 int* __restrict__ degi, int E) {
  int e = blockIdx.x * blockDim.x + threadIdx.x;
  if (e >= E) return;
  int is32 = *flag;
  int d = edge_val(ei32, ei64, is32, E + e);  // dst row of edge_index
  atomicAdd(&degi[d], 1);
}

// Single-block exclusive scan over degi -> rowptr/cursor; also dinv = rsqrt(deg+1).
__global__ void scan_kernel(const int* __restrict__ degi, int* __restrict__ rowptr,
                            int* __restrict__ cursor, float* __restrict__ dinv, int n) {
  __shared__ int part[1024];
  int t = threadIdx.x;
  int CH = (n + 1023) >> 10;
  int b = t * CH;
  int e = min(b + CH, n);
  int s = 0;
  for (int i = b; i < e; ++i) s += degi[i];
  part[t] = s;
  __syncthreads();
  for (int off = 1; off < 1024; off <<= 1) {
    int val = (t >= off) ? part[t - off] : 0;
    __syncthreads();
    part[t] += val;
    __syncthreads();
  }
  int run = (t == 0) ? 0 : part[t - 1];
  for (int i = b; i < e; ++i) {
    rowptr[i] = run;
    cursor[i] = run;
    int d = degi[i];
    dinv[i] = rsqrtf((float)(d + 1));  // +1 self loop; deg>=1 always
    run += d;
  }
  if (t == 1023) rowptr[n] = part[1023];
}

__global__ void scatter_kernel(const int* __restrict__ ei32,
                               const long long* __restrict__ ei64,
                               const int* __restrict__ flag,
                               int* __restrict__ cursor,
                               const float* __restrict__ dinv,
                               int* __restrict__ col, float* __restrict__ normv, int E) {
  int e = blockIdx.x * blockDim.x + threadIdx.x;
  if (e >= E) return;
  int is32 = *flag;
  int s = edge_val(ei32, ei64, is32, e);
  int d = edge_val(ei32, ei64, is32, E + e);
  int pos = atomicAdd(&cursor[d], 1);
  col[pos] = s;
  normv[pos] = dinv[s] * dinv[d];
}

// f32 GEMM: Y[n x HOUT] = X[n x 128] * W[128 x HOUT].
// Block: 256 threads (16 tr x 16 tc), tile 64 rows x HOUT cols,
// per-thread 4 rows x (HOUT/16) cols. X tile in LDS (pad 132 to dodge bank
// conflicts on the stride-16-row reads), W staged in 32-deep k chunks.
template <int HOUT>
__global__ __launch_bounds__(256) void gemm_kernel(const float* __restrict__ X,
                                                   const float* __restrict__ W,
                                                   float* __restrict__ Y, int n) {
  constexpr int KC = 32;
  constexpr int CW = HOUT / 16;  // 8 or 4 cols per thread
  __shared__ float xs[64 * 132];
  __shared__ float ws[KC * HOUT];
  int t = threadIdx.x;
  int tr = t >> 4, tc = t & 15;
  int row0 = blockIdx.x * 64;

  // stage X tile: 64 rows x 128 floats, coalesced float4
#pragma unroll
  for (int j = 0; j < 8; ++j) {
    int f = t + 256 * j;          // float4 index
    int r = f >> 5, kq = f & 31;  // 32 float4 per row
    int gr = row0 + r;
    float4 val = make_float4(0.f, 0.f, 0.f, 0.f);
    if (gr < n) val = *(const float4*)&X[gr * 128 + kq * 4];
    *(float4*)&xs[r * 132 + kq * 4] = val;
  }

  float acc[4][CW];
#pragma unroll
  for (int i = 0; i < 4; ++i)
#pragma unroll
    for (int j = 0; j < CW; ++j) acc[i][j] = 0.f;

  for (int kk = 0; kk < 128 / KC; ++kk) {
    constexpr int NF4 = KC * HOUT / 4;  // float4 count of W chunk
#pragma unroll
    for (int j = 0; j < NF4 / 256; ++j) {
      int f = t + 256 * j;
      int kq = f / (HOUT / 4), cq = f % (HOUT / 4);
      *(float4*)&ws[kq * HOUT + cq * 4] =
          *(const float4*)&W[(kk * KC + kq) * HOUT + cq * 4];
    }
    __syncthreads();
#pragma unroll 4
    for (int k = 0; k < KC; ++k) {
      float xv[4];
#pragma unroll
      for (int i = 0; i < 4; ++i) xv[i] = xs[(tr + i * 16) * 132 + kk * KC + k];
      float wv[CW];
#pragma unroll
      for (int j = 0; j < CW / 4; ++j) {
        float4 w4 = *(const float4*)&ws[k * HOUT + tc * CW + j * 4];
        wv[j * 4 + 0] = w4.x; wv[j * 4 + 1] = w4.y;
        wv[j * 4 + 2] = w4.z; wv[j * 4 + 3] = w4.w;
      }
#pragma unroll
      for (int i = 0; i < 4; ++i)
#pragma unroll
        for (int j = 0; j < CW; ++j) acc[i][j] = fmaf(xv[i], wv[j], acc[i][j]);
    }
    __syncthreads();
  }

#pragma unroll
  for (int i = 0; i < 4; ++i) {
    int gr = row0 + tr + i * 16;
    if (gr < n) {
#pragma unroll
      for (int j = 0; j < CW / 4; ++j) {
        float4 o;
        o.x = acc[i][j * 4 + 0]; o.y = acc[i][j * 4 + 1];
        o.z = acc[i][j * 4 + 2]; o.w = acc[i][j * 4 + 3];
        *(float4*)&Y[gr * HOUT + tc * CW + j * 4] = o;
      }
    }
  }
}

// Aggregation + bias (+BN eval + relu). One wave (64 lanes) per node.
template <int HOUT, bool BN>
__global__ __launch_bounds__(256) void agg_kernel(
    const float* __restrict__ h, const int* __restrict__ rowptr,
    const int* __restrict__ col, const float* __restrict__ normv,
    const float* __restrict__ dinv, const float* __restrict__ bias,
    const float* __restrict__ g, const float* __restrict__ be,
    const float* __restrict__ m, const float* __restrict__ v,
    float* __restrict__ out, int n_nodes) {
  int wid = (blockIdx.x * blockDim.x + threadIdx.x) >> 6;
  int lane = threadIdx.x & 63;
  if (wid >= n_nodes) return;
  int n = wid;
  float dn = dinv[n];
  float sw = dn * dn;  // self-loop norm
  int beg = rowptr[n], end = rowptr[n + 1];

  if (HOUT == 128) {
    float2 hv = *(const float2*)&h[n * 128 + lane * 2];
    float acc0 = sw * hv.x, acc1 = sw * hv.y;
    for (int j = beg; j < end; ++j) {
      int s = col[j];
      float nm = normv[j];
      float2 ev = *(const float2*)&h[s * 128 + lane * 2];
      acc0 = fmaf(nm, ev.x, acc0);
      acc1 = fmaf(nm, ev.y, acc1);
    }
    int c0 = lane * 2;
    float y0 = acc0 + bias[c0];
    float y1 = acc1 + bias[c0 + 1];
    if constexpr (BN) {
      y0 = g[c0] * (y0 - m[c0]) * rsqrtf(v[c0] + 1e-5f) + be[c0];
      y1 = g[c0 + 1] * (y1 - m[c0 + 1]) * rsqrtf(v[c0 + 1] + 1e-5f) + be[c0 + 1];
      y0 = fmaxf(y0, 0.f);
      y1 = fmaxf(y1, 0.f);
    }
    float2 o; o.x = y0; o.y = y1;
    *(float2*)&out[n * 128 + c0] = o;
  } else {
    float acc0 = sw * h[n * HOUT + lane];
    for (int j = beg; j < end; ++j) {
      int s = col[j];
      float nm = normv[j];
      acc0 = fmaf(nm, h[s * HOUT + lane], acc0);
    }
    float y = acc0 + bias[lane];
    if constexpr (BN) {
      y = g[lane] * (y - m[lane]) * rsqrtf(v[lane] + 1e-5f) + be[lane];
      y = fmaxf(y, 0.f);
    }
    out[n * HOUT + lane] = y;
  }
}

extern "C" void kernel_launch(void* const* d_in, const int* in_sizes, int n_in,
                              void* d_out, int out_size, void* d_ws, size_t ws_size,
                              hipStream_t stream) {
  const float* x = (const float*)d_in[0];
  const int* ei32 = (const int*)d_in[1];
  const long long* ei64 = (const long long*)d_in[1];
  const float* W1 = (const float*)d_in[2];
  const float* b1 = (const float*)d_in[3];
  const float* g1 = (const float*)d_in[4];
  const float* be1 = (const float*)d_in[5];
  const float* m1 = (const float*)d_in[6];
  const float* v1 = (const float*)d_in[7];
  const float* W2 = (const float*)d_in[8];
  const float* b2 = (const float*)d_in[9];
  const float* g2 = (const float*)d_in[10];
  const float* be2 = (const float*)d_in[11];
  const float* m2 = (const float*)d_in[12];
  const float* v2 = (const float*)d_in[13];
  const float* W3 = (const float*)d_in[14];
  const float* b3 = (const float*)d_in[15];

  const int N = in_sizes[0] / 128;  // 50000
  const int E = in_sizes[1] / 2;    // 800000

  char* ws = (char*)d_ws;
  size_t off = 0;
  auto alloc = [&](size_t bytes) -> void* {
    void* p = ws + off;
    off = (off + bytes + 255) & ~(size_t)255;
    return p;
  };
  float* dinv = (float*)alloc((size_t)N * 4);
  int* rowptr = (int*)alloc((size_t)(N + 1) * 4);
  int* cursor = (int*)alloc((size_t)N * 4);
  int* degi = (int*)alloc((size_t)N * 4);
  int* col = (int*)alloc((size_t)E * 4);
  float* normv = (float*)alloc((size_t)E * 4);
  int* flag = (int*)alloc(256);
  float* bufA = (float*)alloc((size_t)N * 128 * 4);
  float* bufB = (float*)alloc((size_t)N * 128 * 4);
  (void)ws_size;

  hipMemsetAsync(degi, 0, (size_t)N * 4, stream);
  hipMemsetAsync(flag, 0, 4, stream);
  detect_dtype_kernel<<<1, 256, 0, stream>>>(ei32, flag);
  int eb = (E + 255) / 256;
  count_deg_kernel<<<eb, 256, 0, stream>>>(ei32, ei64, flag, degi, E);
  scan_kernel<<<1, 1024, 0, stream>>>(degi, rowptr, cursor, dinv, N);
  scatter_kernel<<<eb, 256, 0, stream>>>(ei32, ei64, flag, cursor, dinv, col, normv, E);

  int gb = (N + 63) / 64;
  int ab = (N + 3) / 4;  // one wave per node, 4 waves per block

  // layer 1
  gemm_kernel<128><<<gb, 256, 0, stream>>>(x, W1, bufA, N);
  agg_kernel<128, true><<<ab, 256, 0, stream>>>(bufA, rowptr, col, normv, dinv,
                                                b1, g1, be1, m1, v1, bufB, N);
  // layer 2
  gemm_kernel<128><<<gb, 256, 0, stream>>>(bufB, W2, bufA, N);
  agg_kernel<128, true><<<ab, 256, 0, stream>>>(bufA, rowptr, col, normv, dinv,
                                                b2, g2, be2, m2, v2, bufB, N);
  // layer 3
  gemm_kernel<64><<<gb, 256, 0, stream>>>(bufB, W3, bufA, N);
  agg_kernel<64, false><<<ab, 256, 0, stream>>>(bufA, rowptr, col, normv, dinv,
                                                b3, nullptr, nullptr, nullptr,
                                                nullptr, (float*)d_out, N);
}

// Round 2
// 430.493 us; speedup vs baseline: 1.3269x; 1.3269x over previous
//
#include <hip/hip_runtime.h>

// ---------------------------------------------------------------------------
// GCN 3-layer fused pipeline for MI355X.
//   Layer l: h = X @ Wl ; agg[n] = dinv[n]^2*h[n] + sum_{e:dst=n} norm_e*h[src_e]
//            y = agg + b ; (layers 1,2) y = relu(BN_eval(y))
// CSR (by dst) built on device every call. Parallel multi-block scan.
// ---------------------------------------------------------------------------

#define SCAN_CHUNK 1024  // elements per block in the scan; NB = ceil(N/1024) <= 64

// Detect whether edge_index is int32 or int64 on device: if data is int64
// (little-endian), every odd 32-bit word is a high word == 0 (values < 2^31).
__global__ void detect_dtype_kernel(const int* __restrict__ ei32, int* flag) {
  int t = threadIdx.x;
  int any = 0;
  for (int i = 2 * t + 1; i < 8192; i += 512) any |= (ei32[i] != 0);
  if (any) atomicOr(flag, 1);  // 1 => int32 data
}

__device__ __forceinline__ int edge_val(const int* ei32, const long long* ei64,
                                        int is32, int idx) {
  return is32 ? ei32[idx] : (int)ei64[idx];
}

__global__ void count_deg_kernel(const int* __restrict__ ei32,
                                 const long long* __restrict__ ei64,
                                 const int* __restrict__ flag,
                                 int* __restrict__ degi, int E) {
  int e = blockIdx.x * blockDim.x + threadIdx.x;
  if (e >= E) return;
  int is32 = *flag;
  int d = edge_val(ei32, ei64, is32, E + e);  // dst row of edge_index
  atomicAdd(&degi[d], 1);
}

// ---- parallel scan over degi ----------------------------------------------
// k1: per-block sums (SCAN_CHUNK elems / block, 256 threads, int4 loads)
__global__ __launch_bounds__(256) void scan_partial_kernel(
    const int* __restrict__ degi, int* __restrict__ bsum, int n) {
  __shared__ int wsum[4];
  int b = blockIdx.x, t = threadIdx.x;
  int lane = t & 63, wv = t >> 6;
  int i0 = b * SCAN_CHUNK + t * 4;
  int4 d4 = make_int4(0, 0, 0, 0);
  if (i0 + 3 < n) d4 = *(const int4*)&degi[i0];
  else {
    if (i0 < n) d4.x = degi[i0];
    if (i0 + 1 < n) d4.y = degi[i0 + 1];
    if (i0 + 2 < n) d4.z = degi[i0 + 2];
  }
  int s = d4.x + d4.y + d4.z + d4.w;
#pragma unroll
  for (int off = 32; off; off >>= 1) s += __shfl_xor(s, off);
  if (lane == 0) wsum[wv] = s;
  __syncthreads();
  if (t == 0) bsum[b] = wsum[0] + wsum[1] + wsum[2] + wsum[3];
}

// k2: one wave exclusive-scans the <=64 block sums; writes rowptr[n] = total.
__global__ void scan_bsum_kernel(const int* __restrict__ bsum,
                                 int* __restrict__ boff,
                                 int* __restrict__ rowptr, int nb, int n) {
  int t = threadIdx.x;  // 64
  int v = (t < nb) ? bsum[t] : 0;
  int inc = v;
#pragma unroll
  for (int off = 1; off < 64; off <<= 1) {
    int u = __shfl_up(inc, off);
    if (t >= off) inc += u;
  }
  boff[t] = inc - v;  // exclusive
  if (t == 63) rowptr[n] = inc;
}

// k3: per-block local scan + global offset; writes rowptr/cursor/dinv coalesced.
__global__ __launch_bounds__(256) void scan_write_kernel(
    const int* __restrict__ degi, const int* __restrict__ boff,
    int* __restrict__ rowptr, int* __restrict__ cursor,
    float* __restrict__ dinv, int n) {
  __shared__ int woff[4];
  int b = blockIdx.x, t = threadIdx.x;
  int lane = t & 63, wv = t >> 6;
  int i0 = b * SCAN_CHUNK + t * 4;
  int4 d4 = make_int4(0, 0, 0, 0);
  if (i0 + 3 < n) d4 = *(const int4*)&degi[i0];
  else {
    if (i0 < n) d4.x = degi[i0];
    if (i0 + 1 < n) d4.y = degi[i0 + 1];
    if (i0 + 2 < n) d4.z = degi[i0 + 2];
  }
  int tsum = d4.x + d4.y + d4.z + d4.w;
  int inc = tsum;
#pragma unroll
  for (int off = 1; off < 64; off <<= 1) {
    int u = __shfl_up(inc, off);
    if (lane >= off) inc += u;
  }
  if (lane == 63) woff[wv] = inc;
  __syncthreads();
  if (t == 0) {
    int r = 0;
#pragma unroll
    for (int w = 0; w < 4; ++w) { int sw = woff[w]; woff[w] = r; r += sw; }
  }
  __syncthreads();
  int p = inc - tsum + woff[wv] + boff[b];
  int dg[4] = {d4.x, d4.y, d4.z, d4.w};
#pragma unroll
  for (int j = 0; j < 4; ++j) {
    int i = i0 + j;
    if (i < n) {
      rowptr[i] = p;
      cursor[i] = p;
      dinv[i] = rsqrtf((float)(dg[j] + 1));  // +1 self loop
      p += dg[j];
    }
  }
}
// ---------------------------------------------------------------------------

__global__ void scatter_kernel(const int* __restrict__ ei32,
                               const long long* __restrict__ ei64,
                               const int* __restrict__ flag,
                               int* __restrict__ cursor,
                               const float* __restrict__ dinv,
                               int* __restrict__ col, float* __restrict__ normv, int E) {
  int e = blockIdx.x * blockDim.x + threadIdx.x;
  if (e >= E) return;
  int is32 = *flag;
  int s = edge_val(ei32, ei64, is32, e);
  int d = edge_val(ei32, ei64, is32, E + e);
  int pos = atomicAdd(&cursor[d], 1);
  col[pos] = s;
  normv[pos] = dinv[s] * dinv[d];
}

// f32 GEMM: Y[n x HOUT] = X[n x 128] * W[128 x HOUT].
template <int HOUT>
__global__ __launch_bounds__(256) void gemm_kernel(const float* __restrict__ X,
                                                   const float* __restrict__ W,
                                                   float* __restrict__ Y, int n) {
  constexpr int KC = 32;
  constexpr int CW = HOUT / 16;  // 8 or 4 cols per thread
  __shared__ float xs[64 * 132];
  __shared__ float ws[KC * HOUT];
  int t = threadIdx.x;
  int tr = t >> 4, tc = t & 15;
  int row0 = blockIdx.x * 64;

#pragma unroll
  for (int j = 0; j < 8; ++j) {
    int f = t + 256 * j;
    int r = f >> 5, kq = f & 31;
    int gr = row0 + r;
    float4 val = make_float4(0.f, 0.f, 0.f, 0.f);
    if (gr < n) val = *(const float4*)&X[gr * 128 + kq * 4];
    *(float4*)&xs[r * 132 + kq * 4] = val;
  }

  float acc[4][CW];
#pragma unroll
  for (int i = 0; i < 4; ++i)
#pragma unroll
    for (int j = 0; j < CW; ++j) acc[i][j] = 0.f;

  for (int kk = 0; kk < 128 / KC; ++kk) {
    constexpr int NF4 = KC * HOUT / 4;
#pragma unroll
    for (int j = 0; j < NF4 / 256; ++j) {
      int f = t + 256 * j;
      int kq = f / (HOUT / 4), cq = f % (HOUT / 4);
      *(float4*)&ws[kq * HOUT + cq * 4] =
          *(const float4*)&W[(kk * KC + kq) * HOUT + cq * 4];
    }
    __syncthreads();
#pragma unroll 4
    for (int k = 0; k < KC; ++k) {
      float xv[4];
#pragma unroll
      for (int i = 0; i < 4; ++i) xv[i] = xs[(tr + i * 16) * 132 + kk * KC + k];
      float wv[CW];
#pragma unroll
      for (int j = 0; j < CW / 4; ++j) {
        float4 w4 = *(const float4*)&ws[k * HOUT + tc * CW + j * 4];
        wv[j * 4 + 0] = w4.x; wv[j * 4 + 1] = w4.y;
        wv[j * 4 + 2] = w4.z; wv[j * 4 + 3] = w4.w;
      }
#pragma unroll
      for (int i = 0; i < 4; ++i)
#pragma unroll
        for (int j = 0; j < CW; ++j) acc[i][j] = fmaf(xv[i], wv[j], acc[i][j]);
    }
    __syncthreads();
  }

#pragma unroll
  for (int i = 0; i < 4; ++i) {
    int gr = row0 + tr + i * 16;
    if (gr < n) {
#pragma unroll
      for (int j = 0; j < CW / 4; ++j) {
        float4 o;
        o.x = acc[i][j * 4 + 0]; o.y = acc[i][j * 4 + 1];
        o.z = acc[i][j * 4 + 2]; o.w = acc[i][j * 4 + 3];
        *(float4*)&Y[gr * HOUT + tc * CW + j * 4] = o;
      }
    }
  }
}

// Aggregation + bias (+BN eval + relu). HOUT=128: one wave/node (float2/lane).
// HOUT=64: two nodes/wave (32 lanes x float2 each).
template <int HOUT, bool BN>
__global__ __launch_bounds__(256) void agg_kernel(
    const float* __restrict__ h, const int* __restrict__ rowptr,
    const int* __restrict__ col, const float* __restrict__ normv,
    const float* __restrict__ dinv, const float* __restrict__ bias,
    const float* __restrict__ g, const float* __restrict__ be,
    const float* __restrict__ m, const float* __restrict__ v,
    float* __restrict__ out, int n_nodes) {
  int wid = (blockIdx.x * blockDim.x + threadIdx.x) >> 6;
  int lane = threadIdx.x & 63;

  if (HOUT == 128) {
    int n = wid;
    if (n >= n_nodes) return;
    float dn = dinv[n];
    float sw = dn * dn;
    int beg = rowptr[n], end = rowptr[n + 1];
    float2 hv = *(const float2*)&h[n * 128 + lane * 2];
    float acc0 = sw * hv.x, acc1 = sw * hv.y;
    for (int j = beg; j < end; ++j) {
      int s = col[j];
      float nm = normv[j];
      float2 ev = *(const float2*)&h[s * 128 + lane * 2];
      acc0 = fmaf(nm, ev.x, acc0);
      acc1 = fmaf(nm, ev.y, acc1);
    }
    int c0 = lane * 2;
    float y0 = acc0 + bias[c0];
    float y1 = acc1 + bias[c0 + 1];
    if constexpr (BN) {
      y0 = g[c0] * (y0 - m[c0]) * rsqrtf(v[c0] + 1e-5f) + be[c0];
      y1 = g[c0 + 1] * (y1 - m[c0 + 1]) * rsqrtf(v[c0 + 1] + 1e-5f) + be[c0 + 1];
      y0 = fmaxf(y0, 0.f);
      y1 = fmaxf(y1, 0.f);
    }
    float2 o; o.x = y0; o.y = y1;
    *(float2*)&out[n * 128 + c0] = o;
  } else {
    // two nodes per wave: half = lane>>5 selects node, 32 lanes x float2 = 64 cols
    int n = wid * 2 + (lane >> 5);
    if (n >= n_nodes) return;
    int hl = lane & 31;
    float dn = dinv[n];
    float sw = dn * dn;
    int beg = rowptr[n], end = rowptr[n + 1];
    float2 hv = *(const float2*)&h[n * 64 + hl * 2];
    float acc0 = sw * hv.x, acc1 = sw * hv.y;
    for (int j = beg; j < end; ++j) {
      int s = col[j];
      float nm = normv[j];
      float2 ev = *(const float2*)&h[s * 64 + hl * 2];
      acc0 = fmaf(nm, ev.x, acc0);
      acc1 = fmaf(nm, ev.y, acc1);
    }
    int c0 = hl * 2;
    float y0 = acc0 + bias[c0];
    float y1 = acc1 + bias[c0 + 1];
    float2 o; o.x = y0; o.y = y1;
    *(float2*)&out[n * 64 + c0] = o;
  }
}

extern "C" void kernel_launch(void* const* d_in, const int* in_sizes, int n_in,
                              void* d_out, int out_size, void* d_ws, size_t ws_size,
                              hipStream_t stream) {
  const float* x = (const float*)d_in[0];
  const int* ei32 = (const int*)d_in[1];
  const long long* ei64 = (const long long*)d_in[1];
  const float* W1 = (const float*)d_in[2];
  const float* b1 = (const float*)d_in[3];
  const float* g1 = (const float*)d_in[4];
  const float* be1 = (const float*)d_in[5];
  const float* m1 = (const float*)d_in[6];
  const float* v1 = (const float*)d_in[7];
  const float* W2 = (const float*)d_in[8];
  const float* b2 = (const float*)d_in[9];
  const float* g2 = (const float*)d_in[10];
  const float* be2 = (const float*)d_in[11];
  const float* m2 = (const float*)d_in[12];
  const float* v2 = (const float*)d_in[13];
  const float* W3 = (const float*)d_in[14];
  const float* b3 = (const float*)d_in[15];

  const int N = in_sizes[0] / 128;  // 50000
  const int E = in_sizes[1] / 2;    // 800000

  char* ws = (char*)d_ws;
  size_t off = 0;
  auto alloc = [&](size_t bytes) -> void* {
    void* p = ws + off;
    off = (off + bytes + 255) & ~(size_t)255;
    return p;
  };
  float* dinv = (float*)alloc((size_t)N * 4);
  int* rowptr = (int*)alloc((size_t)(N + 1) * 4);
  int* cursor = (int*)alloc((size_t)N * 4);
  int* degi = (int*)alloc((size_t)N * 4);
  int* col = (int*)alloc((size_t)E * 4);
  float* normv = (float*)alloc((size_t)E * 4);
  int* flag = (int*)alloc(256);
  int* bsum = (int*)alloc(64 * 4);
  int* boff = (int*)alloc(64 * 4);
  float* bufA = (float*)alloc((size_t)N * 128 * 4);
  float* bufB = (float*)alloc((size_t)N * 128 * 4);
  (void)ws_size;

  hipMemsetAsync(degi, 0, (size_t)N * 4, stream);
  hipMemsetAsync(flag, 0, 4, stream);
  detect_dtype_kernel<<<1, 256, 0, stream>>>(ei32, flag);
  int eb = (E + 255) / 256;
  count_deg_kernel<<<eb, 256, 0, stream>>>(ei32, ei64, flag, degi, E);
  int nb = (N + SCAN_CHUNK - 1) / SCAN_CHUNK;  // 49 <= 64
  scan_partial_kernel<<<nb, 256, 0, stream>>>(degi, bsum, N);
  scan_bsum_kernel<<<1, 64, 0, stream>>>(bsum, boff, rowptr, nb, N);
  scan_write_kernel<<<nb, 256, 0, stream>>>(degi, boff, rowptr, cursor, dinv, N);
  scatter_kernel<<<eb, 256, 0, stream>>>(ei32, ei64, flag, cursor, dinv, col, normv, E);

  int gb = (N + 63) / 64;
  int ab128 = (N + 3) / 4;        // one wave per node, 4 waves per block
  int ab64 = (N + 7) / 8;         // two nodes per wave

  // layer 1
  gemm_kernel<128><<<gb, 256, 0, stream>>>(x, W1, bufA, N);
  agg_kernel<128, true><<<ab128, 256, 0, stream>>>(bufA, rowptr, col, normv, dinv,
                                                   b1, g1, be1, m1, v1, bufB, N);
  // layer 2
  gemm_kernel<128><<<gb, 256, 0, stream>>>(bufB, W2, bufA, N);
  agg_kernel<128, true><<<ab128, 256, 0, stream>>>(bufA, rowptr, col, normv, dinv,
                                                   b2, g2, be2, m2, v2, bufB, N);
  // layer 3
  gemm_kernel<64><<<gb, 256, 0, stream>>>(bufB, W3, bufA, N);
  agg_kernel<64, false><<<ab64, 256, 0, stream>>>(bufA, rowptr, col, normv, dinv,
                                                  b3, nullptr, nullptr, nullptr,
                                                  nullptr, (float*)d_out, N);
}

// Round 3
// 312.200 us; speedup vs baseline: 1.8297x; 1.3789x over previous
//
#include <hip/hip_runtime.h>

// ---------------------------------------------------------------------------
// GCN 3-layer fused pipeline for MI355X.
//   Layer l: H = X @ Wl (bf16 out) ;
//   agg[n]  = dinv[n]^2*H[n] + sum_{e:dst=n} dinv[src]*dinv[n]*H[src]  (f32)
//   y = agg + b ; (layers 1,2) y = relu(BN_eval(y))
// CSR (by dst) built on device every call. Gathered H stored bf16 to halve
// random-gather traffic; all accumulation f32.
// ---------------------------------------------------------------------------

#define SCAN_CHUNK 1024

__device__ __forceinline__ float blo(unsigned p) {
  return __uint_as_float(p << 16);
}
__device__ __forceinline__ float bhi(unsigned p) {
  return __uint_as_float(p & 0xffff0000u);
}
__device__ __forceinline__ unsigned short f2b(float f) {
  unsigned u = __float_as_uint(f);
  unsigned r = (u + 0x7fffu + ((u >> 16) & 1u)) >> 16;  // RTNE
  return (unsigned short)r;
}

// int32 vs int64 edge_index detection: int64 high words are all zero.
__global__ void detect_dtype_kernel(const int* __restrict__ ei32, int* flag) {
  int t = threadIdx.x;
  int any = 0;
  for (int i = 2 * t + 1; i < 8192; i += 512) any |= (ei32[i] != 0);
  if (any) atomicOr(flag, 1);  // 1 => int32 data
}

__device__ __forceinline__ int edge_val(const int* ei32, const long long* ei64,
                                        int is32, int idx) {
  return is32 ? ei32[idx] : (int)ei64[idx];
}

__global__ void count_deg_kernel(const int* __restrict__ ei32,
                                 const long long* __restrict__ ei64,
                                 const int* __restrict__ flag,
                                 int* __restrict__ degi, int E) {
  int e = blockIdx.x * blockDim.x + threadIdx.x;
  if (e >= E) return;
  int is32 = *flag;
  int d = edge_val(ei32, ei64, is32, E + e);
  atomicAdd(&degi[d], 1);
}

// ---- parallel scan over degi ----------------------------------------------
__global__ __launch_bounds__(256) void scan_partial_kernel(
    const int* __restrict__ degi, int* __restrict__ bsum, int n) {
  __shared__ int wsum[4];
  int b = blockIdx.x, t = threadIdx.x;
  int lane = t & 63, wv = t >> 6;
  int i0 = b * SCAN_CHUNK + t * 4;
  int4 d4 = make_int4(0, 0, 0, 0);
  if (i0 + 3 < n) d4 = *(const int4*)&degi[i0];
  else {
    if (i0 < n) d4.x = degi[i0];
    if (i0 + 1 < n) d4.y = degi[i0 + 1];
    if (i0 + 2 < n) d4.z = degi[i0 + 2];
  }
  int s = d4.x + d4.y + d4.z + d4.w;
#pragma unroll
  for (int off = 32; off; off >>= 1) s += __shfl_xor(s, off);
  if (lane == 0) wsum[wv] = s;
  __syncthreads();
  if (t == 0) bsum[b] = wsum[0] + wsum[1] + wsum[2] + wsum[3];
}

__global__ void scan_bsum_kernel(const int* __restrict__ bsum,
                                 int* __restrict__ boff,
                                 int* __restrict__ rowptr, int nb, int n) {
  int t = threadIdx.x;  // 64
  int v = (t < nb) ? bsum[t] : 0;
  int inc = v;
#pragma unroll
  for (int off = 1; off < 64; off <<= 1) {
    int u = __shfl_up(inc, off);
    if (t >= off) inc += u;
  }
  boff[t] = inc - v;
  if (t == 63) rowptr[n] = inc;
}

__global__ __launch_bounds__(256) void scan_write_kernel(
    const int* __restrict__ degi, const int* __restrict__ boff,
    int* __restrict__ rowptr, int* __restrict__ cursor,
    float* __restrict__ dinv, int n) {
  __shared__ int woff[4];
  int b = blockIdx.x, t = threadIdx.x;
  int lane = t & 63, wv = t >> 6;
  int i0 = b * SCAN_CHUNK + t * 4;
  int4 d4 = make_int4(0, 0, 0, 0);
  if (i0 + 3 < n) d4 = *(const int4*)&degi[i0];
  else {
    if (i0 < n) d4.x = degi[i0];
    if (i0 + 1 < n) d4.y = degi[i0 + 1];
    if (i0 + 2 < n) d4.z = degi[i0 + 2];
  }
  int tsum = d4.x + d4.y + d4.z + d4.w;
  int inc = tsum;
#pragma unroll
  for (int off = 1; off < 64; off <<= 1) {
    int u = __shfl_up(inc, off);
    if (lane >= off) inc += u;
  }
  if (lane == 63) woff[wv] = inc;
  __syncthreads();
  if (t == 0) {
    int r = 0;
#pragma unroll
    for (int w = 0; w < 4; ++w) { int sw = woff[w]; woff[w] = r; r += sw; }
  }
  __syncthreads();
  int p = inc - tsum + woff[wv] + boff[b];
  int dg[4] = {d4.x, d4.y, d4.z, d4.w};
#pragma unroll
  for (int j = 0; j < 4; ++j) {
    int i = i0 + j;
    if (i < n) {
      rowptr[i] = p;
      cursor[i] = p;
      dinv[i] = rsqrtf((float)(dg[j] + 1));  // +1 self loop
      p += dg[j];
    }
  }
}
// ---------------------------------------------------------------------------

// Only col (src id) stored; norm recomputed in agg from L2-resident dinv.
__global__ void scatter_kernel(const int* __restrict__ ei32,
                               const long long* __restrict__ ei64,
                               const int* __restrict__ flag,
                               int* __restrict__ cursor,
                               int* __restrict__ col, int E) {
  int e = blockIdx.x * blockDim.x + threadIdx.x;
  if (e >= E) return;
  int is32 = *flag;
  int s = edge_val(ei32, ei64, is32, e);
  int d = edge_val(ei32, ei64, is32, E + e);
  int pos = atomicAdd(&cursor[d], 1);
  col[pos] = s;
}

// f32 GEMM: H[n x HOUT](bf16) = X[n x 128](f32) * W[128 x HOUT](f32).
template <int HOUT>
__global__ __launch_bounds__(256) void gemm_kernel(const float* __restrict__ X,
                                                   const float* __restrict__ W,
                                                   unsigned short* __restrict__ Y,
                                                   int n) {
  constexpr int KC = 32;
  constexpr int CW = HOUT / 16;  // 8 or 4 cols per thread
  __shared__ float xs[64 * 132];
  __shared__ float ws[KC * HOUT];
  int t = threadIdx.x;
  int tr = t >> 4, tc = t & 15;
  int row0 = blockIdx.x * 64;

#pragma unroll
  for (int j = 0; j < 8; ++j) {
    int f = t + 256 * j;
    int r = f >> 5, kq = f & 31;
    int gr = row0 + r;
    float4 val = make_float4(0.f, 0.f, 0.f, 0.f);
    if (gr < n) val = *(const float4*)&X[gr * 128 + kq * 4];
    *(float4*)&xs[r * 132 + kq * 4] = val;
  }

  float acc[4][CW];
#pragma unroll
  for (int i = 0; i < 4; ++i)
#pragma unroll
    for (int j = 0; j < CW; ++j) acc[i][j] = 0.f;

  for (int kk = 0; kk < 128 / KC; ++kk) {
    constexpr int NF4 = KC * HOUT / 4;
#pragma unroll
    for (int j = 0; j < NF4 / 256; ++j) {
      int f = t + 256 * j;
      int kq = f / (HOUT / 4), cq = f % (HOUT / 4);
      *(float4*)&ws[kq * HOUT + cq * 4] =
          *(const float4*)&W[(kk * KC + kq) * HOUT + cq * 4];
    }
    __syncthreads();
#pragma unroll 4
    for (int k = 0; k < KC; ++k) {
      float xv[4];
#pragma unroll
      for (int i = 0; i < 4; ++i) xv[i] = xs[(tr + i * 16) * 132 + kk * KC + k];
      float wv[CW];
#pragma unroll
      for (int j = 0; j < CW / 4; ++j) {
        float4 w4 = *(const float4*)&ws[k * HOUT + tc * CW + j * 4];
        wv[j * 4 + 0] = w4.x; wv[j * 4 + 1] = w4.y;
        wv[j * 4 + 2] = w4.z; wv[j * 4 + 3] = w4.w;
      }
#pragma unroll
      for (int i = 0; i < 4; ++i)
#pragma unroll
        for (int j = 0; j < CW; ++j) acc[i][j] = fmaf(xv[i], wv[j], acc[i][j]);
    }
    __syncthreads();
  }

#pragma unroll
  for (int i = 0; i < 4; ++i) {
    int gr = row0 + tr + i * 16;
    if (gr < n) {
      unsigned pk[CW / 2];
#pragma unroll
      for (int j = 0; j < CW / 2; ++j)
        pk[j] = (unsigned)f2b(acc[i][2 * j]) |
                ((unsigned)f2b(acc[i][2 * j + 1]) << 16);
      if constexpr (CW == 8) {
        uint4 o; o.x = pk[0]; o.y = pk[1]; o.z = pk[2]; o.w = pk[3];
        *(uint4*)&Y[gr * HOUT + tc * CW] = o;
      } else {
        uint2 o; o.x = pk[0]; o.y = pk[1];
        *(uint2*)&Y[gr * HOUT + tc * CW] = o;
      }
    }
  }
}

// Aggregation + bias (+BN eval + relu). bf16 H rows gathered, f32 accum.
// HOUT=128: one wave/node (uint = 2 bf16 per lane).
// HOUT=64: two nodes/wave (32 lanes x uint each).
template <int HOUT, bool BN>
__global__ __launch_bounds__(256) void agg_kernel(
    const unsigned short* __restrict__ h, const int* __restrict__ rowptr,
    const int* __restrict__ col, const float* __restrict__ dinv,
    const float* __restrict__ bias,
    const float* __restrict__ g, const float* __restrict__ be,
    const float* __restrict__ m, const float* __restrict__ v,
    float* __restrict__ out, int n_nodes) {
  int wid = (blockIdx.x * blockDim.x + threadIdx.x) >> 6;
  int lane = threadIdx.x & 63;
  const unsigned* hu = (const unsigned*)h;

  constexpr int RW = HOUT / 2;        // uints per row (64 or 32)
  int n, sub;
  if (HOUT == 128) {
    n = wid; sub = lane;
  } else {
    n = wid * 2 + (lane >> 5); sub = lane & 31;
  }
  if (n >= n_nodes) return;

  float dn = dinv[n];
  int beg = rowptr[n], end = rowptr[n + 1];
  unsigned selfp = hu[(size_t)n * RW + sub];
  float acc0 = dn * dn * blo(selfp);
  float acc1 = dn * dn * bhi(selfp);

  int j = beg;
  for (; j + 3 < end; j += 4) {
    int s0 = col[j], s1 = col[j + 1], s2 = col[j + 2], s3 = col[j + 3];
    float w0 = dn * dinv[s0], w1 = dn * dinv[s1];
    float w2 = dn * dinv[s2], w3 = dn * dinv[s3];
    unsigned p0 = hu[(size_t)s0 * RW + sub];
    unsigned p1 = hu[(size_t)s1 * RW + sub];
    unsigned p2 = hu[(size_t)s2 * RW + sub];
    unsigned p3 = hu[(size_t)s3 * RW + sub];
    acc0 = fmaf(w0, blo(p0), acc0); acc1 = fmaf(w0, bhi(p0), acc1);
    acc0 = fmaf(w1, blo(p1), acc0); acc1 = fmaf(w1, bhi(p1), acc1);
    acc0 = fmaf(w2, blo(p2), acc0); acc1 = fmaf(w2, bhi(p2), acc1);
    acc0 = fmaf(w3, blo(p3), acc0); acc1 = fmaf(w3, bhi(p3), acc1);
  }
  for (; j < end; ++j) {
    int s = col[j];
    float w = dn * dinv[s];
    unsigned p = hu[(size_t)s * RW + sub];
    acc0 = fmaf(w, blo(p), acc0);
    acc1 = fmaf(w, bhi(p), acc1);
  }

  int c0 = sub * 2;
  float y0 = acc0 + bias[c0];
  float y1 = acc1 + bias[c0 + 1];
  if constexpr (BN) {
    y0 = g[c0] * (y0 - m[c0]) * rsqrtf(v[c0] + 1e-5f) + be[c0];
    y1 = g[c0 + 1] * (y1 - m[c0 + 1]) * rsqrtf(v[c0 + 1] + 1e-5f) + be[c0 + 1];
    y0 = fmaxf(y0, 0.f);
    y1 = fmaxf(y1, 0.f);
  }
  float2 o; o.x = y0; o.y = y1;
  *(float2*)&out[(size_t)n * HOUT + c0] = o;
}

extern "C" void kernel_launch(void* const* d_in, const int* in_sizes, int n_in,
                              void* d_out, int out_size, void* d_ws, size_t ws_size,
                              hipStream_t stream) {
  const float* x = (const float*)d_in[0];
  const int* ei32 = (const int*)d_in[1];
  const long long* ei64 = (const long long*)d_in[1];
  const float* W1 = (const float*)d_in[2];
  const float* b1 = (const float*)d_in[3];
  const float* g1 = (const float*)d_in[4];
  const float* be1 = (const float*)d_in[5];
  const float* m1 = (const float*)d_in[6];
  const float* v1 = (const float*)d_in[7];
  const float* W2 = (const float*)d_in[8];
  const float* b2 = (const float*)d_in[9];
  const float* g2 = (const float*)d_in[10];
  const float* be2 = (const float*)d_in[11];
  const float* m2 = (const float*)d_in[12];
  const float* v2 = (const float*)d_in[13];
  const float* W3 = (const float*)d_in[14];
  const float* b3 = (const float*)d_in[15];

  const int N = in_sizes[0] / 128;  // 50000
  const int E = in_sizes[1] / 2;    // 800000

  char* ws = (char*)d_ws;
  size_t off = 0;
  auto alloc = [&](size_t bytes) -> void* {
    void* p = ws + off;
    off = (off + bytes + 255) & ~(size_t)255;
    return p;
  };
  float* dinv = (float*)alloc((size_t)N * 4);
  int* rowptr = (int*)alloc((size_t)(N + 1) * 4);
  int* cursor = (int*)alloc((size_t)N * 4);
  int* degi = (int*)alloc((size_t)N * 4);
  int* col = (int*)alloc((size_t)E * 4);
  int* flag = (int*)alloc(256);
  int* bsum = (int*)alloc(64 * 4);
  int* boff = (int*)alloc(64 * 4);
  unsigned short* hbuf = (unsigned short*)alloc((size_t)N * 128 * 2);  // bf16
  float* ybuf = (float*)alloc((size_t)N * 128 * 4);
  (void)ws_size;

  hipMemsetAsync(degi, 0, (size_t)N * 4, stream);
  hipMemsetAsync(flag, 0, 4, stream);
  detect_dtype_kernel<<<1, 256, 0, stream>>>(ei32, flag);
  int eb = (E + 255) / 256;
  count_deg_kernel<<<eb, 256, 0, stream>>>(ei32, ei64, flag, degi, E);
  int nb = (N + SCAN_CHUNK - 1) / SCAN_CHUNK;  // 49 <= 64
  scan_partial_kernel<<<nb, 256, 0, stream>>>(degi, bsum, N);
  scan_bsum_kernel<<<1, 64, 0, stream>>>(bsum, boff, rowptr, nb, N);
  scan_write_kernel<<<nb, 256, 0, stream>>>(degi, boff, rowptr, cursor, dinv, N);
  scatter_kernel<<<eb, 256, 0, stream>>>(ei32, ei64, flag, cursor, col, E);

  int gb = (N + 63) / 64;
  int ab128 = (N + 3) / 4;   // one wave per node
  int ab64 = (N + 7) / 8;    // two nodes per wave

  // layer 1
  gemm_kernel<128><<<gb, 256, 0, stream>>>(x, W1, hbuf, N);
  agg_kernel<128, true><<<ab128, 256, 0, stream>>>(hbuf, rowptr, col, dinv,
                                                   b1, g1, be1, m1, v1, ybuf, N);
  // layer 2
  gemm_kernel<128><<<gb, 256, 0, stream>>>(ybuf, W2, hbuf, N);
  agg_kernel<128, true><<<ab128, 256, 0, stream>>>(hbuf, rowptr, col, dinv,
                                                   b2, g2, be2, m2, v2, ybuf, N);
  // layer 3
  gemm_kernel<64><<<gb, 256, 0, stream>>>(ybuf, W3, hbuf, N);
  agg_kernel<64, false><<<ab64, 256, 0, stream>>>(hbuf, rowptr, col, dinv,
                                                  b3, nullptr, nullptr, nullptr,
                                                  nullptr, (float*)d_out, N);
}

// Round 4
// 252.028 us; speedup vs baseline: 2.2666x; 1.2388x over previous
//
#include <hip/hip_runtime.h>

// ---------------------------------------------------------------------------
// GCN 3-layer fused pipeline for MI355X.
//   Layer l: H = X @ Wl (bf16 out) ;
//   agg[n]  = dinv[n]^2*H[n] + sum_{e:dst=n} dinv[src]*dinv[n]*H[src]  (f32)
//   y = agg + b ; (layers 1,2) y = relu(BN_eval(y))
// CSR built per call via deterministic two-level binning (no global atomics):
//   A: per-chunk LDS histogram over dst buckets -> counts_T[bucket][chunk]
//   scan(counts_T) -> offs (each (bucket,chunk) gets contiguous run)
//   C: scatter (src,dst) pairs into bucketed array, dense per-run writes
//   D: per-bucket degree histogram (LDS) -> degi, coalesced
//   scan(degi) -> rowptr, dinv
//   E: per-bucket col assembly in LDS -> coalesced col writes
// ---------------------------------------------------------------------------

#define SCAN_CHUNK 1024
#define NCHUNK 256        // edge chunks (pass A/C blocks)
#define BSHIFT 8          // dsts per bucket = 256
#define BWID 256
#define ECAP 8192         // LDS col stage capacity per bucket (mean 4096)

__device__ __forceinline__ float blo(unsigned p) { return __uint_as_float(p << 16); }
__device__ __forceinline__ float bhi(unsigned p) { return __uint_as_float(p & 0xffff0000u); }
__device__ __forceinline__ unsigned short f2b(float f) {
  unsigned u = __float_as_uint(f);
  unsigned r = (u + 0x7fffu + ((u >> 16) & 1u)) >> 16;  // RTNE
  return (unsigned short)r;
}

// int32 vs int64 edge_index detection: int64 high words are all zero.
__global__ void detect_dtype_kernel(const int* __restrict__ ei32, int* flag) {
  int t = threadIdx.x;
  int any = 0;
  for (int i = 2 * t + 1; i < 8192; i += 512) any |= (ei32[i] != 0);
  if (any) atomicOr(flag, 1);  // 1 => int32 data
}

__device__ __forceinline__ int edge_val(const int* ei32, const long long* ei64,
                                        int is32, int idx) {
  return is32 ? ei32[idx] : (int)ei64[idx];
}

// ---- pass A: per-chunk bucket histogram -----------------------------------
__global__ __launch_bounds__(256) void bin_hist_kernel(
    const int* __restrict__ ei32, const long long* __restrict__ ei64,
    const int* __restrict__ flag, int* __restrict__ counts, int E, int nbk) {
  __shared__ int hist[BWID];
  int k = blockIdx.x, t = threadIdx.x;
  hist[t] = 0;
  __syncthreads();
  int is32 = *flag;
  int CH = (E + NCHUNK - 1) / NCHUNK;
  int e0 = k * CH, e1 = min(e0 + CH, E);
  for (int e = e0 + t; e < e1; e += 256) {
    int d = edge_val(ei32, ei64, is32, E + e);
    atomicAdd(&hist[d >> BSHIFT], 1);
  }
  __syncthreads();
  if (t < nbk) counts[t * NCHUNK + k] = hist[t];
}

// ---- generic parallel scan (3 kernels) ------------------------------------
__global__ __launch_bounds__(256) void scan_partial_kernel(
    const int* __restrict__ src, int* __restrict__ bsum, int n) {
  __shared__ int wsum[4];
  int b = blockIdx.x, t = threadIdx.x;
  int lane = t & 63, wv = t >> 6;
  int i0 = b * SCAN_CHUNK + t * 4;
  int4 d4 = make_int4(0, 0, 0, 0);
  if (i0 + 3 < n) d4 = *(const int4*)&src[i0];
  else {
    if (i0 < n) d4.x = src[i0];
    if (i0 + 1 < n) d4.y = src[i0 + 1];
    if (i0 + 2 < n) d4.z = src[i0 + 2];
  }
  int s = d4.x + d4.y + d4.z + d4.w;
#pragma unroll
  for (int off = 32; off; off >>= 1) s += __shfl_xor(s, off);
  if (lane == 0) wsum[wv] = s;
  __syncthreads();
  if (t == 0) bsum[b] = wsum[0] + wsum[1] + wsum[2] + wsum[3];
}

__global__ void scan_bsum_kernel(const int* __restrict__ bsum,
                                 int* __restrict__ boff,
                                 int* __restrict__ outp, int nb, int n) {
  int t = threadIdx.x;  // 64
  int v = (t < nb) ? bsum[t] : 0;
  int inc = v;
#pragma unroll
  for (int off = 1; off < 64; off <<= 1) {
    int u = __shfl_up(inc, off);
    if (t >= off) inc += u;
  }
  boff[t] = inc - v;
  if (t == 63) outp[n] = inc;  // total
}

// DEG=true: outp=rowptr, also writes dinv=rsqrt(deg+1). DEG=false: plain scan.
template <bool DEG>
__global__ __launch_bounds__(256) void scan_write_kernel(
    const int* __restrict__ src, const int* __restrict__ boff,
    int* __restrict__ outp, float* __restrict__ dinv, int n) {
  __shared__ int woff[4];
  int b = blockIdx.x, t = threadIdx.x;
  int lane = t & 63, wv = t >> 6;
  int i0 = b * SCAN_CHUNK + t * 4;
  int4 d4 = make_int4(0, 0, 0, 0);
  if (i0 + 3 < n) d4 = *(const int4*)&src[i0];
  else {
    if (i0 < n) d4.x = src[i0];
    if (i0 + 1 < n) d4.y = src[i0 + 1];
    if (i0 + 2 < n) d4.z = src[i0 + 2];
  }
  int tsum = d4.x + d4.y + d4.z + d4.w;
  int inc = tsum;
#pragma unroll
  for (int off = 1; off < 64; off <<= 1) {
    int u = __shfl_up(inc, off);
    if (lane >= off) inc += u;
  }
  if (lane == 63) woff[wv] = inc;
  __syncthreads();
  if (t == 0) {
    int r = 0;
#pragma unroll
    for (int w = 0; w < 4; ++w) { int sw = woff[w]; woff[w] = r; r += sw; }
  }
  __syncthreads();
  int p = inc - tsum + woff[wv] + boff[b];
  int dg[4] = {d4.x, d4.y, d4.z, d4.w};
#pragma unroll
  for (int j = 0; j < 4; ++j) {
    int i = i0 + j;
    if (i < n) {
      outp[i] = p;
      if constexpr (DEG) dinv[i] = rsqrtf((float)(dg[j] + 1));  // +1 self loop
      p += dg[j];
    }
  }
}

// ---- pass C: scatter (src,dst) into bucketed runs -------------------------
__global__ __launch_bounds__(256) void bin_scatter_kernel(
    const int* __restrict__ ei32, const long long* __restrict__ ei64,
    const int* __restrict__ flag, const int* __restrict__ offs,
    int2* __restrict__ pairs, int E, int nbk) {
  __shared__ int cur[BWID];
  int k = blockIdx.x, t = threadIdx.x;
  if (t < nbk) cur[t] = offs[t * NCHUNK + k];
  __syncthreads();
  int is32 = *flag;
  int CH = (E + NCHUNK - 1) / NCHUNK;
  int e0 = k * CH, e1 = min(e0 + CH, E);
  for (int e = e0 + t; e < e1; e += 256) {
    int s = edge_val(ei32, ei64, is32, e);
    int d = edge_val(ei32, ei64, is32, E + e);
    int pos = atomicAdd(&cur[d >> BSHIFT], 1);
    pairs[pos] = make_int2(s, d);
  }
}

// ---- pass D: per-bucket degree histogram ----------------------------------
__global__ __launch_bounds__(256) void bucket_deg_kernel(
    const int2* __restrict__ pairs, const int* __restrict__ offs,
    int* __restrict__ degi, int E, int n, int nbk) {
  __shared__ int deg[BWID];
  int b = blockIdx.x, t = threadIdx.x;
  deg[t] = 0;
  __syncthreads();
  int base = offs[b * NCHUNK];
  int end = (b + 1 < nbk) ? offs[(b + 1) * NCHUNK] : E;
  for (int i = base + t; i < end; i += 256) {
    int d = pairs[i].y;
    atomicAdd(&deg[d & (BWID - 1)], 1);
  }
  __syncthreads();
  int idx = b * BWID + t;
  if (idx < n) degi[idx] = deg[t];
}

// ---- pass E: assemble col per bucket in LDS, write coalesced --------------
__global__ __launch_bounds__(256) void bucket_col_kernel(
    const int2* __restrict__ pairs, const int* __restrict__ offs,
    const int* __restrict__ rowptr, int* __restrict__ col,
    int E, int n, int nbk) {
  __shared__ int cur[BWID];
  __shared__ int stage[ECAP];
  int b = blockIdx.x, t = threadIdx.x;
  int rowbase = rowptr[b * BWID];
  int idx = b * BWID + t;
  cur[t] = ((idx < n) ? rowptr[idx] : rowptr[n]) - rowbase;
  __syncthreads();
  int base = offs[b * NCHUNK];
  int end = (b + 1 < nbk) ? offs[(b + 1) * NCHUNK] : E;
  for (int i = base + t; i < end; i += 256) {
    int2 p = pairs[i];
    int pos = atomicAdd(&cur[p.y & (BWID - 1)], 1);
    if (pos < ECAP) stage[pos] = p.x;
  }
  __syncthreads();
  int hi = b * BWID + BWID;
  int nE = ((hi < n) ? rowptr[hi] : rowptr[n]) - rowbase;
  for (int i = t; i < nE; i += 256) col[rowbase + i] = stage[i];
}

// ---- GEMM: H[n x HOUT](bf16) = X[n x 128](f32) * W[128 x HOUT](f32) -------
template <int HOUT>
__global__ __launch_bounds__(256) void gemm_kernel(const float* __restrict__ X,
                                                   const float* __restrict__ W,
                                                   unsigned short* __restrict__ Y,
                                                   int n) {
  constexpr int KC = 32;
  constexpr int CW = HOUT / 16;  // 8 or 4 cols per thread
  __shared__ float xs[64 * 132];
  __shared__ float ws[KC * HOUT];
  int t = threadIdx.x;
  int tr = t >> 4, tc = t & 15;
  int row0 = blockIdx.x * 64;

#pragma unroll
  for (int j = 0; j < 8; ++j) {
    int f = t + 256 * j;
    int r = f >> 5, kq = f & 31;
    int gr = row0 + r;
    float4 val = make_float4(0.f, 0.f, 0.f, 0.f);
    if (gr < n) val = *(const float4*)&X[gr * 128 + kq * 4];
    *(float4*)&xs[r * 132 + kq * 4] = val;
  }

  float acc[4][CW];
#pragma unroll
  for (int i = 0; i < 4; ++i)
#pragma unroll
    for (int j = 0; j < CW; ++j) acc[i][j] = 0.f;

  for (int kk = 0; kk < 128 / KC; ++kk) {
    constexpr int NF4 = KC * HOUT / 4;
#pragma unroll
    for (int j = 0; j < NF4 / 256; ++j) {
      int f = t + 256 * j;
      int kq = f / (HOUT / 4), cq = f % (HOUT / 4);
      *(float4*)&ws[kq * HOUT + cq * 4] =
          *(const float4*)&W[(kk * KC + kq) * HOUT + cq * 4];
    }
    __syncthreads();
#pragma unroll 4
    for (int k = 0; k < KC; ++k) {
      float xv[4];
#pragma unroll
      for (int i = 0; i < 4; ++i) xv[i] = xs[(tr + i * 16) * 132 + kk * KC + k];
      float wv[CW];
#pragma unroll
      for (int j = 0; j < CW / 4; ++j) {
        float4 w4 = *(const float4*)&ws[k * HOUT + tc * CW + j * 4];
        wv[j * 4 + 0] = w4.x; wv[j * 4 + 1] = w4.y;
        wv[j * 4 + 2] = w4.z; wv[j * 4 + 3] = w4.w;
      }
#pragma unroll
      for (int i = 0; i < 4; ++i)
#pragma unroll
        for (int j = 0; j < CW; ++j) acc[i][j] = fmaf(xv[i], wv[j], acc[i][j]);
    }
    __syncthreads();
  }

#pragma unroll
  for (int i = 0; i < 4; ++i) {
    int gr = row0 + tr + i * 16;
    if (gr < n) {
      unsigned pk[CW / 2];
#pragma unroll
      for (int j = 0; j < CW / 2; ++j)
        pk[j] = (unsigned)f2b(acc[i][2 * j]) |
                ((unsigned)f2b(acc[i][2 * j + 1]) << 16);
      if constexpr (CW == 8) {
        uint4 o; o.x = pk[0]; o.y = pk[1]; o.z = pk[2]; o.w = pk[3];
        *(uint4*)&Y[gr * HOUT + tc * CW] = o;
      } else {
        uint2 o; o.x = pk[0]; o.y = pk[1];
        *(uint2*)&Y[gr * HOUT + tc * CW] = o;
      }
    }
  }
}

// ---- aggregation + bias (+BN eval + relu) ---------------------------------
template <int HOUT, bool BN>
__global__ __launch_bounds__(256) void agg_kernel(
    const unsigned short* __restrict__ h, const int* __restrict__ rowptr,
    const int* __restrict__ col, const float* __restrict__ dinv,
    const float* __restrict__ bias,
    const float* __restrict__ g, const float* __restrict__ be,
    const float* __restrict__ m, const float* __restrict__ v,
    float* __restrict__ out, int n_nodes) {
  int wid = (blockIdx.x * blockDim.x + threadIdx.x) >> 6;
  int lane = threadIdx.x & 63;
  const unsigned* hu = (const unsigned*)h;

  constexpr int RW = HOUT / 2;  // uints per row
  int n, sub;
  if (HOUT == 128) {
    n = wid; sub = lane;
  } else {
    n = wid * 2 + (lane >> 5); sub = lane & 31;
  }
  if (n >= n_nodes) return;

  float dn = dinv[n];
  int beg = rowptr[n], end = rowptr[n + 1];
  unsigned selfp = hu[(size_t)n * RW + sub];
  float acc0 = dn * dn * blo(selfp);
  float acc1 = dn * dn * bhi(selfp);

  int j = beg;
  for (; j + 3 < end; j += 4) {
    int s0 = col[j], s1 = col[j + 1], s2 = col[j + 2], s3 = col[j + 3];
    float w0 = dn * dinv[s0], w1 = dn * dinv[s1];
    float w2 = dn * dinv[s2], w3 = dn * dinv[s3];
    unsigned p0 = hu[(size_t)s0 * RW + sub];
    unsigned p1 = hu[(size_t)s1 * RW + sub];
    unsigned p2 = hu[(size_t)s2 * RW + sub];
    unsigned p3 = hu[(size_t)s3 * RW + sub];
    acc0 = fmaf(w0, blo(p0), acc0); acc1 = fmaf(w0, bhi(p0), acc1);
    acc0 = fmaf(w1, blo(p1), acc0); acc1 = fmaf(w1, bhi(p1), acc1);
    acc0 = fmaf(w2, blo(p2), acc0); acc1 = fmaf(w2, bhi(p2), acc1);
    acc0 = fmaf(w3, blo(p3), acc0); acc1 = fmaf(w3, bhi(p3), acc1);
  }
  for (; j < end; ++j) {
    int s = col[j];
    float w = dn * dinv[s];
    unsigned p = hu[(size_t)s * RW + sub];
    acc0 = fmaf(w, blo(p), acc0);
    acc1 = fmaf(w, bhi(p), acc1);
  }

  int c0 = sub * 2;
  float y0 = acc0 + bias[c0];
  float y1 = acc1 + bias[c0 + 1];
  if constexpr (BN) {
    y0 = g[c0] * (y0 - m[c0]) * rsqrtf(v[c0] + 1e-5f) + be[c0];
    y1 = g[c0 + 1] * (y1 - m[c0 + 1]) * rsqrtf(v[c0 + 1] + 1e-5f) + be[c0 + 1];
    y0 = fmaxf(y0, 0.f);
    y1 = fmaxf(y1, 0.f);
  }
  float2 o; o.x = y0; o.y = y1;
  *(float2*)&out[(size_t)n * HOUT + c0] = o;
}

extern "C" void kernel_launch(void* const* d_in, const int* in_sizes, int n_in,
                              void* d_out, int out_size, void* d_ws, size_t ws_size,
                              hipStream_t stream) {
  const float* x = (const float*)d_in[0];
  const int* ei32 = (const int*)d_in[1];
  const long long* ei64 = (const long long*)d_in[1];
  const float* W1 = (const float*)d_in[2];
  const float* b1 = (const float*)d_in[3];
  const float* g1 = (const float*)d_in[4];
  const float* be1 = (const float*)d_in[5];
  const float* m1 = (const float*)d_in[6];
  const float* v1 = (const float*)d_in[7];
  const float* W2 = (const float*)d_in[8];
  const float* b2 = (const float*)d_in[9];
  const float* g2 = (const float*)d_in[10];
  const float* be2 = (const float*)d_in[11];
  const float* m2 = (const float*)d_in[12];
  const float* v2 = (const float*)d_in[13];
  const float* W3 = (const float*)d_in[14];
  const float* b3 = (const float*)d_in[15];

  const int N = in_sizes[0] / 128;  // 50000
  const int E = in_sizes[1] / 2;    // 800000
  const int NBK = (N + BWID - 1) / BWID;  // 196 (must be <= 256)
  const int NC = NBK * NCHUNK;            // 50176

  char* ws = (char*)d_ws;
  size_t off = 0;
  auto alloc = [&](size_t bytes) -> void* {
    void* p = ws + off;
    off = (off + bytes + 255) & ~(size_t)255;
    return p;
  };
  float* dinv = (float*)alloc((size_t)N * 4);
  int* rowptr = (int*)alloc((size_t)(N + 1) * 4);
  int* degi = (int*)alloc((size_t)N * 4);
  int* counts = (int*)alloc((size_t)(NC + 1) * 4);
  int* offs = (int*)alloc((size_t)(NC + 1) * 4);
  int* col = (int*)alloc((size_t)E * 4);
  int2* pairs = (int2*)alloc((size_t)E * 8);
  int* flag = (int*)alloc(256);
  int* bsum = (int*)alloc(64 * 4);
  int* boff = (int*)alloc(64 * 4);
  unsigned short* hbuf = (unsigned short*)alloc((size_t)N * 128 * 2);  // bf16
  float* ybuf = (float*)alloc((size_t)N * 128 * 4);
  (void)ws_size;

  hipMemsetAsync(flag, 0, 4, stream);
  detect_dtype_kernel<<<1, 256, 0, stream>>>(ei32, flag);

  // CSR build via binning
  bin_hist_kernel<<<NCHUNK, 256, 0, stream>>>(ei32, ei64, flag, counts, E, NBK);
  int nbC = (NC + SCAN_CHUNK - 1) / SCAN_CHUNK;  // 50
  scan_partial_kernel<<<nbC, 256, 0, stream>>>(counts, bsum, NC);
  scan_bsum_kernel<<<1, 64, 0, stream>>>(bsum, boff, offs, nbC, NC);
  scan_write_kernel<false><<<nbC, 256, 0, stream>>>(counts, boff, offs, nullptr, NC);
  bin_scatter_kernel<<<NCHUNK, 256, 0, stream>>>(ei32, ei64, flag, offs, pairs, E, NBK);
  bucket_deg_kernel<<<NBK, 256, 0, stream>>>(pairs, offs, degi, E, N, NBK);
  int nbN = (N + SCAN_CHUNK - 1) / SCAN_CHUNK;  // 49
  scan_partial_kernel<<<nbN, 256, 0, stream>>>(degi, bsum, N);
  scan_bsum_kernel<<<1, 64, 0, stream>>>(bsum, boff, rowptr, nbN, N);
  scan_write_kernel<true><<<nbN, 256, 0, stream>>>(degi, boff, rowptr, dinv, N);
  bucket_col_kernel<<<NBK, 256, 0, stream>>>(pairs, offs, rowptr, col, E, N, NBK);

  int gb = (N + 63) / 64;
  int ab128 = (N + 3) / 4;  // one wave per node
  int ab64 = (N + 7) / 8;   // two nodes per wave

  // layer 1
  gemm_kernel<128><<<gb, 256, 0, stream>>>(x, W1, hbuf, N);
  agg_kernel<128, true><<<ab128, 256, 0, stream>>>(hbuf, rowptr, col, dinv,
                                                   b1, g1, be1, m1, v1, ybuf, N);
  // layer 2
  gemm_kernel<128><<<gb, 256, 0, stream>>>(ybuf, W2, hbuf, N);
  agg_kernel<128, true><<<ab128, 256, 0, stream>>>(hbuf, rowptr, col, dinv,
                                                   b2, g2, be2, m2, v2, ybuf, N);
  // layer 3
  gemm_kernel<64><<<gb, 256, 0, stream>>>(ybuf, W3, hbuf, N);
  agg_kernel<64, false><<<ab64, 256, 0, stream>>>(hbuf, rowptr, col, dinv,
                                                  b3, nullptr, nullptr, nullptr,
                                                  nullptr, (float*)d_out, N);
}

// Round 5
// 181.068 us; speedup vs baseline: 3.1548x; 1.3919x over previous
//
#include <hip/hip_runtime.h>

// ---------------------------------------------------------------------------
// GCN 3-layer fused pipeline for MI355X.
//   Layer l: H = bf16mfma(A_bf16 @ Wl_bf16) -> hbuf (bf16)
//   agg[n]  = dinv[n]^2*H[n] + sum_{e:dst=n} dinv[src]*dinv[n]*H[src]  (f32 acc)
//   y = agg + b ; (layers 1,2) y = relu(BN_eval(y)) -> bf16 ybuf ; layer3 f32 out
// CSR built per call via deterministic two-level binning (no global atomics).
// ---------------------------------------------------------------------------

#define SCAN_CHUNK 1024
#define NCHUNK 256   // edge chunks (pass A/C blocks)
#define BSHIFT 8     // dsts per bucket = 256
#define BWID 256
#define ECAP 8192    // LDS col stage capacity per bucket (mean 4096)

typedef __attribute__((ext_vector_type(8))) short bf16x8;
typedef __attribute__((ext_vector_type(4))) float f32x4;

__device__ __forceinline__ float blo(unsigned p) { return __uint_as_float(p << 16); }
__device__ __forceinline__ float bhi(unsigned p) { return __uint_as_float(p & 0xffff0000u); }
__device__ __forceinline__ unsigned short f2b(float f) {
  unsigned u = __float_as_uint(f);
  unsigned r = (u + 0x7fffu + ((u >> 16) & 1u)) >> 16;  // RTNE
  return (unsigned short)r;
}

// int32 vs int64 edge_index detection: int64 high words are all zero.
__global__ void detect_dtype_kernel(const int* __restrict__ ei32, int* flag) {
  int t = threadIdx.x;
  int any = 0;
  for (int i = 2 * t + 1; i < 8192; i += 512) any |= (ei32[i] != 0);
  if (any) atomicOr(flag, 1);  // 1 => int32 data
}

__device__ __forceinline__ int edge_val(const int* ei32, const long long* ei64,
                                        int is32, int idx) {
  return is32 ? ei32[idx] : (int)ei64[idx];
}

// ---- weight prep: Wt[c][k] = bf16(W[k][c]) for all 3 layers ---------------
__global__ void wprep_kernel(const float* __restrict__ W1, const float* __restrict__ W2,
                             const float* __restrict__ W3,
                             unsigned short* __restrict__ Wt1,
                             unsigned short* __restrict__ Wt2,
                             unsigned short* __restrict__ Wt3) {
  int i = blockIdx.x * 256 + threadIdx.x;
  if (i < 16384) {
    int k = i >> 7, c = i & 127;
    Wt1[c * 128 + k] = f2b(W1[i]);
  } else if (i < 32768) {
    int j = i - 16384; int k = j >> 7, c = j & 127;
    Wt2[c * 128 + k] = f2b(W2[j]);
  } else {
    int j = i - 32768;
    if (j < 8192) { int k = j >> 6, c = j & 63; Wt3[c * 128 + k] = f2b(W3[j]); }
  }
}

// ---- pass A: per-chunk bucket histogram -----------------------------------
__global__ __launch_bounds__(256) void bin_hist_kernel(
    const int* __restrict__ ei32, const long long* __restrict__ ei64,
    const int* __restrict__ flag, int* __restrict__ counts, int E, int nbk) {
  __shared__ int hist[BWID];
  int k = blockIdx.x, t = threadIdx.x;
  hist[t] = 0;
  __syncthreads();
  int is32 = *flag;
  int CH = (E + NCHUNK - 1) / NCHUNK;
  int e0 = k * CH, e1 = min(e0 + CH, E);
  for (int e = e0 + t; e < e1; e += 256) {
    int d = edge_val(ei32, ei64, is32, E + e);
    atomicAdd(&hist[d >> BSHIFT], 1);
  }
  __syncthreads();
  if (t < nbk) counts[t * NCHUNK + k] = hist[t];
}

// ---- generic parallel scan (3 kernels) ------------------------------------
__global__ __launch_bounds__(256) void scan_partial_kernel(
    const int* __restrict__ src, int* __restrict__ bsum, int n) {
  __shared__ int wsum[4];
  int b = blockIdx.x, t = threadIdx.x;
  int lane = t & 63, wv = t >> 6;
  int i0 = b * SCAN_CHUNK + t * 4;
  int4 d4 = make_int4(0, 0, 0, 0);
  if (i0 + 3 < n) d4 = *(const int4*)&src[i0];
  else {
    if (i0 < n) d4.x = src[i0];
    if (i0 + 1 < n) d4.y = src[i0 + 1];
    if (i0 + 2 < n) d4.z = src[i0 + 2];
  }
  int s = d4.x + d4.y + d4.z + d4.w;
#pragma unroll
  for (int off = 32; off; off >>= 1) s += __shfl_xor(s, off);
  if (lane == 0) wsum[wv] = s;
  __syncthreads();
  if (t == 0) bsum[b] = wsum[0] + wsum[1] + wsum[2] + wsum[3];
}

__global__ void scan_bsum_kernel(const int* __restrict__ bsum,
                                 int* __restrict__ boff,
                                 int* __restrict__ outp, int nb, int n) {
  int t = threadIdx.x;  // 64
  int v = (t < nb) ? bsum[t] : 0;
  int inc = v;
#pragma unroll
  for (int off = 1; off < 64; off <<= 1) {
    int u = __shfl_up(inc, off);
    if (t >= off) inc += u;
  }
  boff[t] = inc - v;
  if (t == 63) outp[n] = inc;  // total
}

template <bool DEG>
__global__ __launch_bounds__(256) void scan_write_kernel(
    const int* __restrict__ src, const int* __restrict__ boff,
    int* __restrict__ outp, float* __restrict__ dinv, int n) {
  __shared__ int woff[4];
  int b = blockIdx.x, t = threadIdx.x;
  int lane = t & 63, wv = t >> 6;
  int i0 = b * SCAN_CHUNK + t * 4;
  int4 d4 = make_int4(0, 0, 0, 0);
  if (i0 + 3 < n) d4 = *(const int4*)&src[i0];
  else {
    if (i0 < n) d4.x = src[i0];
    if (i0 + 1 < n) d4.y = src[i0 + 1];
    if (i0 + 2 < n) d4.z = src[i0 + 2];
  }
  int tsum = d4.x + d4.y + d4.z + d4.w;
  int inc = tsum;
#pragma unroll
  for (int off = 1; off < 64; off <<= 1) {
    int u = __shfl_up(inc, off);
    if (lane >= off) inc += u;
  }
  if (lane == 63) woff[wv] = inc;
  __syncthreads();
  if (t == 0) {
    int r = 0;
#pragma unroll
    for (int w = 0; w < 4; ++w) { int sw = woff[w]; woff[w] = r; r += sw; }
  }
  __syncthreads();
  int p = inc - tsum + woff[wv] + boff[b];
  int dg[4] = {d4.x, d4.y, d4.z, d4.w};
#pragma unroll
  for (int j = 0; j < 4; ++j) {
    int i = i0 + j;
    if (i < n) {
      outp[i] = p;
      if constexpr (DEG) dinv[i] = rsqrtf((float)(dg[j] + 1));  // +1 self loop
      p += dg[j];
    }
  }
}

// ---- pass C: scatter packed (src | dst_low<<20) into bucketed runs --------
__global__ __launch_bounds__(256) void bin_scatter_kernel(
    const int* __restrict__ ei32, const long long* __restrict__ ei64,
    const int* __restrict__ flag, const int* __restrict__ offs,
    unsigned* __restrict__ pairs, int E, int nbk) {
  __shared__ int cur[BWID];
  int k = blockIdx.x, t = threadIdx.x;
  if (t < nbk) cur[t] = offs[t * NCHUNK + k];
  __syncthreads();
  int is32 = *flag;
  int CH = (E + NCHUNK - 1) / NCHUNK;
  int e0 = k * CH, e1 = min(e0 + CH, E);
  for (int e = e0 + t; e < e1; e += 256) {
    int s = edge_val(ei32, ei64, is32, e);
    int d = edge_val(ei32, ei64, is32, E + e);
    int pos = atomicAdd(&cur[d >> BSHIFT], 1);
    pairs[pos] = (unsigned)s | ((unsigned)(d & (BWID - 1)) << 20);
  }
}

// ---- pass D: per-bucket degree histogram ----------------------------------
__global__ __launch_bounds__(256) void bucket_deg_kernel(
    const unsigned* __restrict__ pairs, const int* __restrict__ offs,
    int* __restrict__ degi, int E, int n, int nbk) {
  __shared__ int deg[BWID];
  int b = blockIdx.x, t = threadIdx.x;
  deg[t] = 0;
  __syncthreads();
  int base = offs[b * NCHUNK];
  int end = (b + 1 < nbk) ? offs[(b + 1) * NCHUNK] : E;
  for (int i = base + t; i < end; i += 256) {
    atomicAdd(&deg[pairs[i] >> 20], 1);
  }
  __syncthreads();
  int idx = b * BWID + t;
  if (idx < n) degi[idx] = deg[t];
}

// ---- pass E: assemble col per bucket in LDS, write coalesced --------------
__global__ __launch_bounds__(256) void bucket_col_kernel(
    const unsigned* __restrict__ pairs, const int* __restrict__ offs,
    const int* __restrict__ rowptr, int* __restrict__ col,
    int E, int n, int nbk) {
  __shared__ int cur[BWID];
  __shared__ int stage[ECAP];
  int b = blockIdx.x, t = threadIdx.x;
  int rowbase = rowptr[b * BWID];
  int idx = b * BWID + t;
  cur[t] = ((idx < n) ? rowptr[idx] : rowptr[n]) - rowbase;
  __syncthreads();
  int base = offs[b * NCHUNK];
  int end = (b + 1 < nbk) ? offs[(b + 1) * NCHUNK] : E;
  for (int i = base + t; i < end; i += 256) {
    unsigned p = pairs[i];
    int pos = atomicAdd(&cur[p >> 20], 1);
    if (pos < ECAP) stage[pos] = (int)(p & 0xFFFFFu);
  }
  __syncthreads();
  int hi = b * BWID + BWID;
  int nE = ((hi < n) ? rowptr[hi] : rowptr[n]) - rowbase;
  for (int i = t; i < nE; i += 256) col[rowbase + i] = stage[i];
}

// ---- MFMA bf16 GEMM: Y[n x HOUT](bf16) = A[n x 128] * Wt^T ----------------
// Wt is [HOUT][128] bf16 (pre-transposed). Block tile 64 x NT, K=128 staged
// fully in LDS with ((row&15)<<4) XOR swizzle for conflict-free ds_read_b128.
template <int HOUT, int ABF16>
__global__ __launch_bounds__(256) void mgemm_kernel(
    const void* __restrict__ Ain, const unsigned short* __restrict__ Wt,
    unsigned short* __restrict__ Y, int n) {
  constexpr int NT = HOUT;  // 128 or 64: full width per block
  __shared__ unsigned char AsB[64 * 256];
  __shared__ unsigned char BsB[NT * 256];
  int t = threadIdx.x;
  int row0 = blockIdx.x * 64;

  // stage A (64 rows x 128 k, bf16, swizzled)
  if constexpr (ABF16) {
    const unsigned short* A = (const unsigned short*)Ain;
#pragma unroll
    for (int jj = 0; jj < 4; ++jj) {
      int f = t + 256 * jj; int r = f >> 4, kq = f & 15;
      uint4 v = make_uint4(0, 0, 0, 0);
      if (row0 + r < n) v = *(const uint4*)&A[(size_t)(row0 + r) * 128 + kq * 8];
      *(uint4*)&AsB[r * 256 + ((kq * 16) ^ ((r & 15) << 4))] = v;
    }
  } else {
    const float* A = (const float*)Ain;
#pragma unroll
    for (int jj = 0; jj < 8; ++jj) {
      int f = t + 256 * jj; int r = f >> 5, kq = f & 31;
      float4 v = make_float4(0.f, 0.f, 0.f, 0.f);
      if (row0 + r < n) v = *(const float4*)&A[(size_t)(row0 + r) * 128 + kq * 4];
      unsigned two0 = (unsigned)f2b(v.x) | ((unsigned)f2b(v.y) << 16);
      unsigned two1 = (unsigned)f2b(v.z) | ((unsigned)f2b(v.w) << 16);
      uint2 o = make_uint2(two0, two1);
      *(uint2*)&AsB[r * 256 + ((kq * 8) ^ ((r & 15) << 4))] = o;
    }
  }
  // stage B: Wt[NT][128] bf16, swizzled
#pragma unroll
  for (int jj = 0; jj < NT / 16; ++jj) {
    int f = t + 256 * jj; int c = f >> 4, kq = f & 15;
    uint4 v = *(const uint4*)&Wt[(size_t)c * 128 + kq * 8];
    *(uint4*)&BsB[c * 256 + ((kq * 16) ^ ((c & 15) << 4))] = v;
  }
  __syncthreads();

  int l = t & 63, wid = t >> 6;
  constexpr int WC = NT / 2;        // wave col extent (64 or 32)
  constexpr int NI = WC / 16;       // col subtiles per wave (4 or 2)
  int wr = (wid >> 1) * 32, wc = (wid & 1) * WC;
  int lr = l & 15, lk = (l >> 4) * 16;  // fragment row/col + k-byte part

  f32x4 acc[2][NI] = {};
#pragma unroll
  for (int ks = 0; ks < 4; ++ks) {
    bf16x8 a[2], b[NI];
#pragma unroll
    for (int mi = 0; mi < 2; ++mi) {
      int r = wr + mi * 16 + lr;
      a[mi] = *(const bf16x8*)&AsB[r * 256 + ((ks * 64 + lk) ^ ((r & 15) << 4))];
    }
#pragma unroll
    for (int ni = 0; ni < NI; ++ni) {
      int c = wc + ni * 16 + lr;
      b[ni] = *(const bf16x8*)&BsB[c * 256 + ((ks * 64 + lk) ^ ((c & 15) << 4))];
    }
#pragma unroll
    for (int mi = 0; mi < 2; ++mi)
#pragma unroll
      for (int ni = 0; ni < NI; ++ni)
        acc[mi][ni] = __builtin_amdgcn_mfma_f32_16x16x32_bf16(a[mi], b[ni],
                                                              acc[mi][ni], 0, 0, 0);
  }

  // epilogue: D col = l&15, row = (l>>4)*4 + reg  (per 16x16 tile)
#pragma unroll
  for (int mi = 0; mi < 2; ++mi) {
#pragma unroll
    for (int reg = 0; reg < 4; ++reg) {
      int gr = row0 + wr + mi * 16 + (l >> 4) * 4 + reg;
      if (gr < n) {
#pragma unroll
        for (int ni = 0; ni < NI; ++ni) {
          int gc = wc + ni * 16 + lr;
          Y[(size_t)gr * HOUT + gc] = f2b(acc[mi][ni][reg]);
        }
      }
    }
  }
}

// ---- aggregation + bias (+BN eval + relu) ---------------------------------
// OUTBF: write bf16 (layers 1,2 feed next MFMA GEMM); else f32 (final out).
template <int HOUT, bool BN, bool OUTBF>
__global__ __launch_bounds__(256) void agg_kernel(
    const unsigned short* __restrict__ h, const int* __restrict__ rowptr,
    const int* __restrict__ col, const float* __restrict__ dinv,
    const float* __restrict__ bias,
    const float* __restrict__ g, const float* __restrict__ be,
    const float* __restrict__ m, const float* __restrict__ v,
    void* __restrict__ out, int n_nodes) {
  int wid = (blockIdx.x * blockDim.x + threadIdx.x) >> 6;
  int lane = threadIdx.x & 63;
  const unsigned* hu = (const unsigned*)h;

  constexpr int RW = HOUT / 2;  // uints per row
  int n, sub;
  if (HOUT == 128) {
    n = wid; sub = lane;
  } else {
    n = wid * 2 + (lane >> 5); sub = lane & 31;
  }
  if (n >= n_nodes) return;

  float dn = dinv[n];
  int beg = rowptr[n], end = rowptr[n + 1];
  unsigned selfp = hu[(size_t)n * RW + sub];
  float acc0 = dn * dn * blo(selfp);
  float acc1 = dn * dn * bhi(selfp);

  int j = beg;
  for (; j + 7 < end; j += 8) {
    int s[8]; float w[8]; unsigned p[8];
#pragma unroll
    for (int u = 0; u < 8; ++u) s[u] = col[j + u];
#pragma unroll
    for (int u = 0; u < 8; ++u) p[u] = hu[(size_t)s[u] * RW + sub];
#pragma unroll
    for (int u = 0; u < 8; ++u) w[u] = dn * dinv[s[u]];
#pragma unroll
    for (int u = 0; u < 8; ++u) {
      acc0 = fmaf(w[u], blo(p[u]), acc0);
      acc1 = fmaf(w[u], bhi(p[u]), acc1);
    }
  }
  for (; j + 3 < end; j += 4) {
    int s[4]; float w[4]; unsigned p[4];
#pragma unroll
    for (int u = 0; u < 4; ++u) s[u] = col[j + u];
#pragma unroll
    for (int u = 0; u < 4; ++u) p[u] = hu[(size_t)s[u] * RW + sub];
#pragma unroll
    for (int u = 0; u < 4; ++u) w[u] = dn * dinv[s[u]];
#pragma unroll
    for (int u = 0; u < 4; ++u) {
      acc0 = fmaf(w[u], blo(p[u]), acc0);
      acc1 = fmaf(w[u], bhi(p[u]), acc1);
    }
  }
  for (; j < end; ++j) {
    int s = col[j];
    float w = dn * dinv[s];
    unsigned p = hu[(size_t)s * RW + sub];
    acc0 = fmaf(w, blo(p), acc0);
    acc1 = fmaf(w, bhi(p), acc1);
  }

  int c0 = sub * 2;
  float y0 = acc0 + bias[c0];
  float y1 = acc1 + bias[c0 + 1];
  if constexpr (BN) {
    y0 = g[c0] * (y0 - m[c0]) * rsqrtf(v[c0] + 1e-5f) + be[c0];
    y1 = g[c0 + 1] * (y1 - m[c0 + 1]) * rsqrtf(v[c0 + 1] + 1e-5f) + be[c0 + 1];
    y0 = fmaxf(y0, 0.f);
    y1 = fmaxf(y1, 0.f);
  }
  if constexpr (OUTBF) {
    unsigned pk = (unsigned)f2b(y0) | ((unsigned)f2b(y1) << 16);
    ((unsigned*)out)[(size_t)n * RW + sub] = pk;
  } else {
    float2 o; o.x = y0; o.y = y1;
    *(float2*)&((float*)out)[(size_t)n * HOUT + c0] = o;
  }
}

extern "C" void kernel_launch(void* const* d_in, const int* in_sizes, int n_in,
                              void* d_out, int out_size, void* d_ws, size_t ws_size,
                              hipStream_t stream) {
  const float* x = (const float*)d_in[0];
  const int* ei32 = (const int*)d_in[1];
  const long long* ei64 = (const long long*)d_in[1];
  const float* W1 = (const float*)d_in[2];
  const float* b1 = (const float*)d_in[3];
  const float* g1 = (const float*)d_in[4];
  const float* be1 = (const float*)d_in[5];
  const float* m1 = (const float*)d_in[6];
  const float* v1 = (const float*)d_in[7];
  const float* W2 = (const float*)d_in[8];
  const float* b2 = (const float*)d_in[9];
  const float* g2 = (const float*)d_in[10];
  const float* be2 = (const float*)d_in[11];
  const float* m2 = (const float*)d_in[12];
  const float* v2 = (const float*)d_in[13];
  const float* W3 = (const float*)d_in[14];
  const float* b3 = (const float*)d_in[15];

  const int N = in_sizes[0] / 128;  // 50000
  const int E = in_sizes[1] / 2;    // 800000
  const int NBK = (N + BWID - 1) / BWID;  // 196 (<= 256)
  const int NC = NBK * NCHUNK;            // 50176

  char* ws = (char*)d_ws;
  size_t off = 0;
  auto alloc = [&](size_t bytes) -> void* {
    void* p = ws + off;
    off = (off + bytes + 255) & ~(size_t)255;
    return p;
  };
  float* dinv = (float*)alloc((size_t)N * 4);
  int* rowptr = (int*)alloc((size_t)(N + 1) * 4);
  int* degi = (int*)alloc((size_t)N * 4);
  int* counts = (int*)alloc((size_t)(NC + 1) * 4);
  int* offs = (int*)alloc((size_t)(NC + 1) * 4);
  int* col = (int*)alloc((size_t)E * 4);
  unsigned* pairs = (unsigned*)alloc((size_t)E * 4);
  int* flag = (int*)alloc(256);
  int* bsum = (int*)alloc(64 * 4);
  int* boff = (int*)alloc(64 * 4);
  unsigned short* wt1 = (unsigned short*)alloc(128 * 128 * 2);
  unsigned short* wt2 = (unsigned short*)alloc(128 * 128 * 2);
  unsigned short* wt3 = (unsigned short*)alloc(128 * 64 * 2);
  unsigned short* hbuf = (unsigned short*)alloc((size_t)N * 128 * 2);  // bf16
  unsigned short* ybuf = (unsigned short*)alloc((size_t)N * 128 * 2);  // bf16
  (void)ws_size;

  hipMemsetAsync(flag, 0, 4, stream);
  detect_dtype_kernel<<<1, 256, 0, stream>>>(ei32, flag);
  wprep_kernel<<<160, 256, 0, stream>>>(W1, W2, W3, wt1, wt2, wt3);

  // CSR build via binning
  bin_hist_kernel<<<NCHUNK, 256, 0, stream>>>(ei32, ei64, flag, counts, E, NBK);
  int nbC = (NC + SCAN_CHUNK - 1) / SCAN_CHUNK;  // 50
  scan_partial_kernel<<<nbC, 256, 0, stream>>>(counts, bsum, NC);
  scan_bsum_kernel<<<1, 64, 0, stream>>>(bsum, boff, offs, nbC, NC);
  scan_write_kernel<false><<<nbC, 256, 0, stream>>>(counts, boff, offs, nullptr, NC);
  bin_scatter_kernel<<<NCHUNK, 256, 0, stream>>>(ei32, ei64, flag, offs, pairs, E, NBK);
  bucket_deg_kernel<<<NBK, 256, 0, stream>>>(pairs, offs, degi, E, N, NBK);
  int nbN = (N + SCAN_CHUNK - 1) / SCAN_CHUNK;  // 49
  scan_partial_kernel<<<nbN, 256, 0, stream>>>(degi, bsum, N);
  scan_bsum_kernel<<<1, 64, 0, stream>>>(bsum, boff, rowptr, nbN, N);
  scan_write_kernel<true><<<nbN, 256, 0, stream>>>(degi, boff, rowptr, dinv, N);
  bucket_col_kernel<<<NBK, 256, 0, stream>>>(pairs, offs, rowptr, col, E, N, NBK);

  int gb = (N + 63) / 64;
  int ab128 = (N + 3) / 4;  // one wave per node
  int ab64 = (N + 7) / 8;   // two nodes per wave

  // layer 1
  mgemm_kernel<128, 0><<<gb, 256, 0, stream>>>(x, wt1, hbuf, N);
  agg_kernel<128, true, true><<<ab128, 256, 0, stream>>>(hbuf, rowptr, col, dinv,
                                                         b1, g1, be1, m1, v1, ybuf, N);
  // layer 2
  mgemm_kernel<128, 1><<<gb, 256, 0, stream>>>(ybuf, wt2, hbuf, N);
  agg_kernel<128, true, true><<<ab128, 256, 0, stream>>>(hbuf, rowptr, col, dinv,
                                                         b2, g2, be2, m2, v2, ybuf, N);
  // layer 3
  mgemm_kernel<64, 1><<<gb, 256, 0, stream>>>(ybuf, wt3, hbuf, N);
  agg_kernel<64, false, false><<<ab64, 256, 0, stream>>>(hbuf, rowptr, col, dinv,
                                                         b3, nullptr, nullptr, nullptr,
                                                         nullptr, d_out, N);
}